// Round 11
// baseline (139.813 us; speedup 1.0000x reference)
//
#include <hip/hip_runtime.h>
#include <stdint.h>

// Problem constants (fixed by setup_inputs).
#define N_LIDAR   8192
#define M_QUERIES 32768   // 1024 rays * 32 samples
#define D_FEAT    128
#define BLOCK     256
#define QPB       64                       // queries owned per block
#define N_BLK     (M_QUERIES / QPB)        // 512 blocks = 2 per CU
#define HALF_N    (N_LIDAR / 2)            // 4096 candidates per wave's half
#define GIT       (HALF_N / 32)            // 128 MFMA tiles per wave per phase
#define STR       (32 * 16)                // shorts per MFMA tile of B

// Filter slack (HW-proven at absmax 0 in rounds 8-10): worst-case
// |e_a - e_exact| <= ~1.8e-3; EPS2 = 0.008 keeps 2.2x margin.
#define EPS2 0.008f

typedef __attribute__((ext_vector_type(8)))  short bf16x8;
typedef __attribute__((ext_vector_type(16))) float f32x16;

// Workspace layout (640 KB of ws):
#define WS_KEYS  0                         // 32768 * 8  u64 exact argmin keys
#define WS_BTAB  262144                    //  8192 * 16 bf16 (32B rows)
#define WS_CPK   524288                    //  8192 float4 (-2lx,-2ly,-2lz,ks)

// Order-preserving float->u32 map (and inverse) for min-reduction.
__device__ __forceinline__ unsigned mapf(float f) {
    unsigned u = __float_as_uint(f);
    return (u & 0x80000000u) ? ~u : (u | 0x80000000u);
}
__device__ __forceinline__ float unmapf(unsigned u) {
    return __uint_as_float((u & 0x80000000u) ? (u ^ 0x80000000u) : ~u);
}

// Split f32 into bf16 hi + bf16 lo (RNE).
__device__ __forceinline__ void bsplit(float v, short& h, short& l) {
    unsigned u = __float_as_uint(v);
    unsigned r = (u + 0x7FFFu + ((u >> 16) & 1u)) & 0xFFFF0000u;
    h = (short)(r >> 16);
    float lo = v - __uint_as_float(r);
    unsigned u2 = __float_as_uint(lo);
    l = (short)((u2 + 0x7FFFu + ((u2 >> 16) & 1u)) >> 16);
}

#define BF_ONE ((short)0x3F80)

// Prep (lidar side only): B table rows encoding the candidate side of
// e_a ~= -2*q.l + ks, plus exact-rescore pack (proven r10).
__global__ __launch_bounds__(BLOCK)
void prep_kernel(const float* __restrict__ lidar,
                 short* __restrict__ Btab, float4* __restrict__ cpack) {
    #pragma clang fp contract(off)
    int i = blockIdx.x * blockDim.x + threadIdx.x;
    float lx = lidar[3 * i + 0], ly = lidar[3 * i + 1], lz = lidar[3 * i + 2];
    float ks = (lx * lx + ly * ly) + lz * lz;   // np rounding order, no FMA
    float Lx = -2.0f * lx, Ly = -2.0f * ly, Lz = -2.0f * lz;  // exact scale
    short xh, xl, yh, yl, zh, zl, kh, kl;
    bsplit(Lx, xh, xl); bsplit(Ly, yh, yl); bsplit(Lz, zh, zl); bsplit(ks, kh, kl);
    short b[16] = {xh, xl, xh, yh, yl, yh, zh, zl, zh,
                   kh, kl, 0, 0, 0, 0, 0};
    ((int4*)(Btab + 16 * i))[0] = *(const int4*)(b);
    ((int4*)(Btab + 16 * i))[1] = *(const int4*)(b + 8);
    cpack[i] = make_float4(Lx, Ly, Lz, ks);
}

// MFMA fragment addressing for v_mfma_f32_32x32x16_bf16 (HW-proven r5-r10):
//   A[m][k]: m = lane&31, k = (lane>>5)*8 + j
//   B[k][n]: n = lane&31, k = (lane>>5)*8 + j
//   C/D    : col = lane&31, row = (reg&3) + 8*(reg>>2) + 4*(lane>>5)
//
// Fused kernel: block owns 64 queries; wave w = (query-group w&1) x
// (candidate-half w>>1). Phase-1 mins from both halves combine in LDS ->
// full-range thresholds; keys stay block-private -> in-kernel gather legal.
// 512 blocks = 2/CU (2 waves/SIMD); 4-deep register prefetch of B covers
// L2 latency. B-traffic = 512 x 512KB = 268 MB L2 (half of r10).
__global__ __launch_bounds__(BLOCK, 2)
void fused_kernel(const float* __restrict__ pts,
                  const short* __restrict__ Btab, const float4* __restrict__ cpack,
                  unsigned long long* __restrict__ keys,
                  const float4* __restrict__ feat, float4* __restrict__ out) {
    #pragma clang fp contract(off)
    __shared__ short    asplit[QPB][16];
    __shared__ float4   qpk[QPB];
    __shared__ unsigned sgmin[QPB];
    const int tid  = threadIdx.x;
    const int lane = tid & 63, wave = tid >> 6;
    const int half8 = lane >> 5, ln = lane & 31;
    const int qg    = wave & 1;          // query group (0..1)
    const int chalf = wave >> 1;         // candidate half (0..1)
    const int qbase = blockIdx.x * QPB;
    const int segbase = chalf * HALF_N;

    // ---- In-block query prep (64 threads) ----
    if (tid < QPB) {
        int q = qbase + tid;
        float x = pts[3 * q + 0], y = pts[3 * q + 1], z = pts[3 * q + 2];
        float qs = (x * x + y * y) + z * z;     // np rounding order, no FMA
        short xh, xl, yh, yl, zh, zl;
        bsplit(x, xh, xl); bsplit(y, yh, yl); bsplit(z, zh, zl);
        short a[16] = {xh, xh, xl, yh, yh, yl, zh, zh, zl,
                       BF_ONE, BF_ONE, 0, 0, 0, 0, 0};
        #pragma unroll
        for (int k = 0; k < 16; ++k) asplit[tid][k] = a[k];
        qpk[tid]   = make_float4(x, y, z, qs);
        sgmin[tid] = 0xFFFFFFFFu;
        __hip_atomic_store(&keys[q], 0xFFFFFFFFFFFFFFFFull,
                           __ATOMIC_RELAXED, __HIP_MEMORY_SCOPE_AGENT);
    }
    __syncthreads();

    const bf16x8 a = *(const bf16x8*)&asplit[qg * 32 + ln][half8 * 8];
    const short* bp = Btab + (segbase + ln) * 16 + half8 * 8;

    // ---------- Phase 1: approx min over this wave's half ----------
    {
        f32x16 m;
        #pragma unroll
        for (int r = 0; r < 16; ++r) m[r] = __builtin_inff();

        bf16x8 b0 = *(const bf16x8*)(bp + 0 * STR);
        bf16x8 b1 = *(const bf16x8*)(bp + 1 * STR);
        bf16x8 b2 = *(const bf16x8*)(bp + 2 * STR);
        bf16x8 b3 = *(const bf16x8*)(bp + 3 * STR);
        for (int g = 0; g < GIT; g += 4) {
            bf16x8 n0, n1, n2, n3;
            const bool more = (g + 4) < GIT;
            if (more) {                       // 4 loads in flight over 4 tiles
                n0 = *(const bf16x8*)(bp + (g + 4) * STR);
                n1 = *(const bf16x8*)(bp + (g + 5) * STR);
                n2 = *(const bf16x8*)(bp + (g + 6) * STR);
                n3 = *(const bf16x8*)(bp + (g + 7) * STR);
            }
            f32x16 z = 0.0f;
            f32x16 a0 = __builtin_amdgcn_mfma_f32_32x32x16_bf16(a, b0, z, 0, 0, 0);
            f32x16 a1 = __builtin_amdgcn_mfma_f32_32x32x16_bf16(a, b1, z, 0, 0, 0);
            f32x16 a2 = __builtin_amdgcn_mfma_f32_32x32x16_bf16(a, b2, z, 0, 0, 0);
            f32x16 a3 = __builtin_amdgcn_mfma_f32_32x32x16_bf16(a, b3, z, 0, 0, 0);
            #pragma unroll
            for (int r = 0; r < 16; ++r) m[r] = fminf(m[r], a0[r]);
            #pragma unroll
            for (int r = 0; r < 16; ++r) m[r] = fminf(m[r], a1[r]);
            #pragma unroll
            for (int r = 0; r < 16; ++r) m[r] = fminf(m[r], a2[r]);
            #pragma unroll
            for (int r = 0; r < 16; ++r) m[r] = fminf(m[r], a3[r]);
            if (more) { b0 = n0; b1 = n1; b2 = n2; b3 = n3; }
        }

        // Butterfly min across the 32 lanes sharing each row.
        #pragma unroll
        for (int off = 16; off >= 1; off >>= 1) {
            #pragma unroll
            for (int r = 0; r < 16; ++r)
                m[r] = fminf(m[r], __shfl_xor(m[r], off));
        }
        if (ln == 0) {
            #pragma unroll
            for (int r = 0; r < 16; ++r) {
                int row = (r & 3) + 8 * (r >> 2) + 4 * half8;
                atomicMin(&sgmin[qg * 32 + row], mapf(m[r]));  // LDS ds_min
            }
        }
    }

    __syncthreads();   // full-range mins ready (both halves merged)

    // ---------- Phase 2: filtered exact rescore over the same half ----------
    {
        float thr[16];
        #pragma unroll
        for (int r = 0; r < 16; ++r) {
            int row = (r & 3) + 8 * (r >> 2) + 4 * half8;
            thr[r] = unmapf(sgmin[qg * 32 + row]) + EPS2;
        }

        bf16x8 b0 = *(const bf16x8*)(bp + 0 * STR);
        bf16x8 b1 = *(const bf16x8*)(bp + 1 * STR);
        bf16x8 b2 = *(const bf16x8*)(bp + 2 * STR);
        bf16x8 b3 = *(const bf16x8*)(bp + 3 * STR);
        for (int g = 0; g < GIT; g += 4) {
            bf16x8 n0, n1, n2, n3;
            const bool more = (g + 4) < GIT;
            if (more) {
                n0 = *(const bf16x8*)(bp + (g + 4) * STR);
                n1 = *(const bf16x8*)(bp + (g + 5) * STR);
                n2 = *(const bf16x8*)(bp + (g + 6) * STR);
                n3 = *(const bf16x8*)(bp + (g + 7) * STR);
            }
            #pragma unroll
            for (int t = 0; t < 4; ++t) {
                bf16x8 bc = (t == 0) ? b0 : (t == 1) ? b1 : (t == 2) ? b2 : b3;
                f32x16 z = 0.0f;
                f32x16 acc = __builtin_amdgcn_mfma_f32_32x32x16_bf16(a, bc, z, 0, 0, 0);
                unsigned long long h = 0;
                #pragma unroll
                for (int r = 0; r < 16; ++r) h |= __ballot(acc[r] < thr[r]);
                if (h) {
                    const int c = segbase + (g + t) * 32 + ln;
                    unsigned mk = 0;
                    #pragma unroll
                    for (int r = 0; r < 16; ++r)
                        mk = (acc[r] < thr[r]) ? (mk | (1u << r)) : mk;
                    while (mk) {   // only hitting lanes iterate (exec-masked)
                        int r = __builtin_ctz(mk); mk &= mk - 1;
                        int row = (r & 3) + 8 * (r >> 2) + 4 * half8;
                        // Exact reference-rounded rescore (proven r1-r10).
                        float4 Q = qpk[qg * 32 + row];
                        float4 C = cpack[c];
                        float cr = (Q.x * C.x + Q.y * C.y) + Q.z * C.z;
                        float t2 = Q.w + cr;        // fl(qs - 2*cross)
                        float d2 = t2 + C.w;        // fl(t + ks)
                        unsigned u = __float_as_uint(d2);
                        u ^= (u >> 31) ? 0xFFFFFFFFu : 0x80000000u;
                        unsigned long long key =
                            ((unsigned long long)u << 13) | (unsigned)c;
                        atomicMin(&keys[qbase + qg * 32 + row], key);
                    }
                }
            }
            if (more) { b0 = n0; b1 = n1; b2 = n2; b3 = n3; }
        }
    }

    __syncthreads();   // all this block's key atomics drained + visible

    // ---------- Phase 3: gather this block's 64 queries ----------
    // 64 queries x 32 float4 = 2048 float4; 256 threads x 8 each.
    #pragma unroll
    for (int e = 0; e < 8; ++e) {
        int elem = tid + e * BLOCK;            // 0..2047
        int q    = qbase + (elem >> 5);
        int l5   = elem & 31;
        unsigned long long key = __hip_atomic_load(&keys[q],
            __ATOMIC_RELAXED, __HIP_MEMORY_SCOPE_AGENT);   // L2 read, skips L1
        int idx = (int)(key & (unsigned long long)(N_LIDAR - 1));
        out[q * (D_FEAT / 4) + l5] = feat[idx * (D_FEAT / 4) + l5];
    }
}

extern "C" void kernel_launch(void* const* d_in, const int* in_sizes, int n_in,
                              void* d_out, int out_size, void* d_ws, size_t ws_size,
                              hipStream_t stream) {
    const float* pts      = (const float*)d_in[0];   // (1,1024,32,3)
    const float* lidar    = (const float*)d_in[1];   // (1,8192,3)
    const float* features = (const float*)d_in[2];   // (1,8192,128)
    float* out = (float*)d_out;                      // (1,1024,32,128)

    char* ws = (char*)d_ws;
    unsigned long long* keys = (unsigned long long*)(ws + WS_KEYS);
    short* Btab = (short*)(ws + WS_BTAB);
    float4* cpack = (float4*)(ws + WS_CPK);

    prep_kernel<<<N_LIDAR / BLOCK, BLOCK, 0, stream>>>(lidar, Btab, cpack);
    fused_kernel<<<N_BLK, BLOCK, 0, stream>>>(
        pts, Btab, cpack, keys, (const float4*)features, (float4*)out);
}